// Round 1
// 388.744 us; speedup vs baseline: 1.0340x; 1.0340x over previous
//
#include <hip/hip_runtime.h>
#include <hip/hip_bf16.h>
#include <type_traits>

#define B_   4
#define C_   512
#define C8_  64
#define HW_  4096

typedef short bf16x8 __attribute__((ext_vector_type(8)));
typedef float f32x4  __attribute__((ext_vector_type(4)));

__device__ __forceinline__ unsigned short f2bf(float f) {
  union { unsigned int i; float f; } x; x.f = f;
  unsigned int r = x.i + 0x7fffu + ((x.i >> 16) & 1u);   // RNE
  return (unsigned short)(r >> 16);
}

#define MFMA(a, b, c) __builtin_amdgcn_mfma_f32_16x16x32_bf16((a), (b), (c), 0, 0, 0)

// ---------------------------------------------------------------------------
// proj: one dispatch for all three projections (unchanged).
//   y==0: Qh[b][m][64] = Wq.total + bq
//   y==1: Kh[b][m][64] = Wk.fe + bk + ht[o][h] + wt[o][w]   (pos folded into K)
//   y>=2: Vn[b][ch][m] = Wv.fe + bv, ch-chunk (y-2)*128
// grid (64, 6, 4), 256 thr.
// ---------------------------------------------------------------------------
__global__ __launch_bounds__(256) void proj_kernel(
    const float* __restrict__ total, const float* __restrict__ fe,
    const float* __restrict__ Wq, const float* __restrict__ bq,
    const float* __restrict__ Wk, const float* __restrict__ bk,
    const float* __restrict__ Wv, const float* __restrict__ bv,
    const float* __restrict__ ht, const float* __restrict__ wt,
    unsigned short* __restrict__ Qh, unsigned short* __restrict__ Kh,
    unsigned short* __restrict__ Vn) {
  __shared__ __align__(16) unsigned short Xs[64 * 72];    // [m][c]
  __shared__ __align__(16) unsigned short Ws[128 * 72];   // [o][c]
  const int t = threadIdx.x;
  const int b = blockIdx.z;
  const int y = blockIdx.y;
  const int m0 = blockIdx.x * 64;
  const int lane = t & 63, w = t >> 6, ln = lane & 15, quad = lane >> 4;

  if (y < 2) {
    // ---------------- Q or K ----------------
    const float* X = (y == 0) ? total : fe;
    const float* W = (y == 0) ? Wq : Wk;
    const float* bias = (y == 0) ? bq : bk;
    unsigned short* dst = (y == 0) ? Qh : Kh;

    f32x4 acc[4];
#pragma unroll
    for (int i = 0; i < 4; ++i) acc[i] = f32x4{0.f, 0.f, 0.f, 0.f};

    for (int kb = 0; kb < 8; ++kb) {
      const int c0 = kb * 64;
#pragma unroll
      for (int i = 0; i < 4; ++i) {        // Ws: 64o x 64c
        int idx = t + i * 256; int o = idx >> 4, c4 = idx & 15;
        float4 wv = *(const float4*)&W[(size_t)o * C_ + c0 + c4 * 4];
        unsigned int p0 = f2bf(wv.x) | ((unsigned int)f2bf(wv.y) << 16);
        unsigned int p1 = f2bf(wv.z) | ((unsigned int)f2bf(wv.w) << 16);
        *(uint2*)&Ws[o * 72 + c4 * 4] = make_uint2(p0, p1);
      }
#pragma unroll
      for (int i = 0; i < 4; ++i) {        // Xs: transpose [c][m] -> [m][c]
        int idx = t + i * 256; int rc = idx >> 4, mq = idx & 15;
        float4 xv = *(const float4*)&X[((size_t)b * C_ + c0 + rc) * HW_ + m0 + mq * 4];
        Xs[(mq * 4 + 0) * 72 + rc] = f2bf(xv.x);
        Xs[(mq * 4 + 1) * 72 + rc] = f2bf(xv.y);
        Xs[(mq * 4 + 2) * 72 + rc] = f2bf(xv.z);
        Xs[(mq * 4 + 3) * 72 + rc] = f2bf(xv.w);
      }
      __syncthreads();
      bf16x8 a0 = *(const bf16x8*)&Xs[(w * 16 + ln) * 72 + quad * 8];
      bf16x8 a1 = *(const bf16x8*)&Xs[(w * 16 + ln) * 72 + 32 + quad * 8];
#pragma unroll
      for (int nt = 0; nt < 4; ++nt) {
        bf16x8 b0 = *(const bf16x8*)&Ws[(nt * 16 + ln) * 72 + quad * 8];
        bf16x8 b1 = *(const bf16x8*)&Ws[(nt * 16 + ln) * 72 + 32 + quad * 8];
        acc[nt] = MFMA(a0, b0, acc[nt]);
        acc[nt] = MFMA(a1, b1, acc[nt]);
      }
      __syncthreads();
    }

    const int h = blockIdx.x;  // m-tile of 64 == one image row
#pragma unroll
    for (int nt = 0; nt < 4; ++nt) {
      const int o = nt * 16 + ln;
      const float bz = bias[o];
      const float hv = (y == 1) ? ht[o * 64 + h] : 0.0f;
#pragma unroll
      for (int r = 0; r < 4; ++r) {
        const int m = m0 + w * 16 + quad * 4 + r;
        float val = acc[nt][r] + bz + hv;
        if (y == 1) val += wt[o * 64 + (m & 63)];
        dst[((size_t)b * HW_ + m) * 64 + o] = f2bf(val);
      }
    }
  } else {
    // ---------------- V chunk ----------------
    const int o0 = (y - 2) * 128;
    f32x4 acc[2][4];
#pragma unroll
    for (int p = 0; p < 2; ++p)
#pragma unroll
      for (int i = 0; i < 4; ++i) acc[p][i] = f32x4{0.f, 0.f, 0.f, 0.f};

    for (int kb = 0; kb < 8; ++kb) {
      const int c0 = kb * 64;
#pragma unroll
      for (int i = 0; i < 8; ++i) {        // Ws: 128o x 64c
        int idx = t + i * 256; int o = idx >> 4, c4 = idx & 15;
        float4 wv = *(const float4*)&Wv[(size_t)(o0 + o) * C_ + c0 + c4 * 4];
        unsigned int p0 = f2bf(wv.x) | ((unsigned int)f2bf(wv.y) << 16);
        unsigned int p1 = f2bf(wv.z) | ((unsigned int)f2bf(wv.w) << 16);
        *(uint2*)&Ws[o * 72 + c4 * 4] = make_uint2(p0, p1);
      }
#pragma unroll
      for (int i = 0; i < 4; ++i) {        // Xs transpose
        int idx = t + i * 256; int rc = idx >> 4, mq = idx & 15;
        float4 xv = *(const float4*)&fe[((size_t)b * C_ + c0 + rc) * HW_ + m0 + mq * 4];
        Xs[(mq * 4 + 0) * 72 + rc] = f2bf(xv.x);
        Xs[(mq * 4 + 1) * 72 + rc] = f2bf(xv.y);
        Xs[(mq * 4 + 2) * 72 + rc] = f2bf(xv.z);
        Xs[(mq * 4 + 3) * 72 + rc] = f2bf(xv.w);
      }
      __syncthreads();
      bf16x8 aW[2][2];
#pragma unroll
      for (int p = 0; p < 2; ++p) {
        aW[p][0] = *(const bf16x8*)&Ws[((w + 4 * p) * 16 + ln) * 72 + quad * 8];
        aW[p][1] = *(const bf16x8*)&Ws[((w + 4 * p) * 16 + ln) * 72 + 32 + quad * 8];
      }
#pragma unroll
      for (int nt = 0; nt < 4; ++nt) {
        bf16x8 b0 = *(const bf16x8*)&Xs[(nt * 16 + ln) * 72 + quad * 8];
        bf16x8 b1 = *(const bf16x8*)&Xs[(nt * 16 + ln) * 72 + 32 + quad * 8];
#pragma unroll
        for (int p = 0; p < 2; ++p) {
          acc[p][nt] = MFMA(aW[p][0], b0, acc[p][nt]);
          acc[p][nt] = MFMA(aW[p][1], b1, acc[p][nt]);
        }
      }
      __syncthreads();
    }

#pragma unroll
    for (int p = 0; p < 2; ++p) {
#pragma unroll
      for (int r = 0; r < 4; ++r) {
        const int ch = o0 + (w + 4 * p) * 16 + quad * 4 + r;
        const float bz = bv[ch];
#pragma unroll
        for (int nt = 0; nt < 4; ++nt) {
          const int m = m0 + nt * 16 + ln;
          Vn[((size_t)b * C_ + ch) * HW_ + m] = f2bf(acc[p][nt][r] + bz);
        }
      }
    }
  }
}

// ---------------------------------------------------------------------------
// flash R6->R7: latency-bound fix (MfmaUtil 13%, occ 20%, HBM 3%):
//   (a) 512 threads / 8 waves, 64 kpos per barrier. Wave w: (qt=w&3, kh=w>>2)
//       computes E[qt-tile][kh-half] for QK^T; owns ch slice w*32..w*32+31 for
//       PV. 16 waves/CU (was 8), barrier rate per kpos halved, ZERO extra
//       traffic (a ch- or q-split of the grid would duplicate K or V reads).
//   (b) raw s_barrier + lgkmcnt(0)-only drain (Ps is the only cross-wave
//       data; K/V/Q register prefetches have no cross-wave hazard) -> global
//       loads stay in flight across the barrier instead of being vmcnt(0)-
//       drained every step by __syncthreads.
//   (c) K/V register fragments single-buffered (reload right after last use)
//       to stay under 128 VGPR for 4 waves/SIMD (launch_bounds(512,4)).
// Safety of 1 barrier + 2 Ps buffers: stores of iter t+2 (buf t&1) happen
// only after barrier(t+1), which no wave passes before its stores of t+1,
// which follow its PV reads of t.
// grid (512), 512 thr.
// ---------------------------------------------------------------------------
__global__ __launch_bounds__(512, 4) void flash_kernel(
    const unsigned short* __restrict__ Qh, const unsigned short* __restrict__ Kh,
    const unsigned short* __restrict__ Vn, const float* __restrict__ fe,
    const float* __restrict__ gamma, float* __restrict__ out) {
  __shared__ __align__(16) unsigned short Ps[2][64 * 72];    // 18.4 KB
  __shared__ float Red[2][64];

  const int t = threadIdx.x;
  const int n = blockIdx.x;
  const int xcd = n & 7;                 // XCD swizzle: one (b, half) per XCD
  const int b = xcd & 3;
  const int ch0 = (xcd >> 2) * 256;
  const int q0 = (n >> 3) * 64;
  const int lane = t & 63, w = t >> 6, ln = lane & 15, quad = lane >> 4;
  const int qt = w & 3;                  // q sub-tile (16 rows) for QK^T
  const int kh = w >> 2;                 // k half (32 kpos) for QK^T

  const unsigned short* Qb = Qh + (size_t)b * HW_ * 64;
  const unsigned short* Kb = Kh + (size_t)b * HW_ * 64;
  const unsigned short* Vb = Vn + ((size_t)b * C_ + ch0) * HW_;

  // Q A-fragments straight from global (row q0+qt*16+ln, cols quad*8..)
  const bf16x8 aq0 = *(const bf16x8*)&Qb[(size_t)(q0 + qt * 16 + ln) * 64 + quad * 8];
  const bf16x8 aq1 = *(const bf16x8*)&Qb[(size_t)(q0 + qt * 16 + ln) * 64 + 32 + quad * 8];

  float Sacc[4] = {0.f, 0.f, 0.f, 0.f};
  f32x4 acc[2][4];
#pragma unroll
  for (int mt = 0; mt < 2; ++mt)
#pragma unroll
    for (int nt = 0; nt < 4; ++nt) acc[mt][nt] = f32x4{0.f, 0.f, 0.f, 0.f};

  bf16x8 kf[2][2];   // [nt_k][c-half], this wave's kh half only
  bf16x8 vf[2][2];   // [mt][kc], ch rows w*32 + mt*16 + ln

  auto loadK = [&](int mk) {
#pragma unroll
    for (int nt = 0; nt < 2; ++nt)
#pragma unroll
      for (int hf = 0; hf < 2; ++hf)
        kf[nt][hf] = *(const bf16x8*)&Kb[(size_t)(mk + kh * 32 + nt * 16 + ln) * 64 + hf * 32 + quad * 8];
  };
  auto loadV = [&](int mk) {
#pragma unroll
    for (int mt = 0; mt < 2; ++mt)
#pragma unroll
      for (int kc = 0; kc < 2; ++kc)
        vf[mt][kc] = *(const bf16x8*)&Vb[(size_t)(w * 32 + mt * 16 + ln) * HW_ + mk + kc * 32 + quad * 8];
  };

  loadK(0);
  loadV(0);

  for (int it = 0; it < 64; ++it) {      // 64 kpos per iteration
    unsigned short* Pcur = Ps[it & 1];
    // QK^T for this wave's (qt, kh): 16 q rows x 32 kpos
    f32x4 e0 = MFMA(aq0, kf[0][0], (f32x4{0.f, 0.f, 0.f, 0.f}));
    e0 = MFMA(aq1, kf[0][1], e0);
    f32x4 e1 = MFMA(aq0, kf[1][0], (f32x4{0.f, 0.f, 0.f, 0.f}));
    e1 = MFMA(aq1, kf[1][1], e1);
    // K prefetch for it+1 (kf dead after the 4 MFMAs above); stays in
    // flight across the raw barrier.
    if (it < 63) loadK((it + 1) * 64);
    // softmax numerators (fixed shift) + inline S accumulation + P stores
#pragma unroll
    for (int r = 0; r < 4; ++r) {
      const float p0 = __expf(e0[r] - 20.0f);
      const float p1 = __expf(e1[r] - 20.0f);
      Sacc[r] += p0 + p1;
      const int qrow = qt * 16 + quad * 4 + r;
      Pcur[qrow * 72 + kh * 32 + ln] = f2bf(p0);
      Pcur[qrow * 72 + kh * 32 + 16 + ln] = f2bf(p1);
    }
    // P stores visible to all waves; do NOT drain vmcnt (prefetches in flight)
    asm volatile("s_waitcnt lgkmcnt(0)" ::: "memory");
    __builtin_amdgcn_s_barrier();
    asm volatile("" ::: "memory");
    // PV: D[ch][q] over 64 kpos in two 32-k chunks
#pragma unroll
    for (int kc = 0; kc < 2; ++kc) {
      bf16x8 bp[4];
#pragma unroll
      for (int nt = 0; nt < 4; ++nt)
        bp[nt] = *(const bf16x8*)&Pcur[(nt * 16 + ln) * 72 + kc * 32 + quad * 8];
#pragma unroll
      for (int mt = 0; mt < 2; ++mt)
#pragma unroll
        for (int nt = 0; nt < 4; ++nt)
          acc[mt][nt] = MFMA(vf[mt][kc], bp[nt], acc[mt][nt]);
    }
    // V prefetch for it+1 (vf dead after PV)
    if (it < 63) loadV((it + 1) * 64);
  }

  // ---- S reduce (per kh half, summed at read) + epilogue ----
#pragma unroll
  for (int r = 0; r < 4; ++r) {
    float s = Sacc[r];
    s += __shfl_xor(s, 1, 16);
    s += __shfl_xor(s, 2, 16);
    s += __shfl_xor(s, 4, 16);
    s += __shfl_xor(s, 8, 16);
    if (ln == 0) Red[kh][qt * 16 + quad * 4 + r] = s;
  }
  __syncthreads();
  float rsv[4];
#pragma unroll
  for (int nt = 0; nt < 4; ++nt)
    rsv[nt] = 1.0f / (Red[0][nt * 16 + ln] + Red[1][nt * 16 + ln]);

  const float g = gamma[0];
#pragma unroll
  for (int mt = 0; mt < 2; ++mt) {
#pragma unroll
    for (int r = 0; r < 4; ++r) {
      const int ch = ch0 + w * 32 + mt * 16 + quad * 4 + r;
      const size_t base = ((size_t)b * C_ + ch) * HW_ + q0;
#pragma unroll
      for (int nt = 0; nt < 4; ++nt) {
        const size_t idx = base + nt * 16 + ln;
        out[idx] = g * (acc[mt][nt][r] * rsv[nt]) + fe[idx];
      }
    }
  }
}

// ---------------------------------------------------------------------------
extern "C" void kernel_launch(void* const* d_in, const int* in_sizes, int n_in,
                              void* d_out, int out_size, void* d_ws, size_t ws_size,
                              hipStream_t stream) {
  const float* fe    = (const float*)d_in[0];
  const float* total = (const float*)d_in[1];
  const float* Wq    = (const float*)d_in[2];
  const float* bq    = (const float*)d_in[3];
  const float* Wk    = (const float*)d_in[4];
  const float* bk    = (const float*)d_in[5];
  const float* Wv    = (const float*)d_in[6];
  const float* bv    = (const float*)d_in[7];
  const float* ht    = (const float*)d_in[8];
  const float* wt    = (const float*)d_in[9];
  const float* gamma = (const float*)d_in[10];
  float* out = (float*)d_out;

  // ws: Qh 2MB | Kh 2MB | Vn 16MB
  unsigned short* Qh = (unsigned short*)d_ws;
  unsigned short* Kh = Qh + (size_t)B_ * HW_ * C8_;
  unsigned short* Vn = Kh + (size_t)B_ * HW_ * C8_;

  proj_kernel<<<dim3(64, 6, B_), 256, 0, stream>>>(total, fe, Wq, bq, Wk, bk,
                                                   Wv, bv, ht, wt, Qh, Kh, Vn);
  flash_kernel<<<dim3(512), 512, 0, stream>>>(Qh, Kh, Vn, fe, gamma, out);
}

// Round 2
// 271.284 us; speedup vs baseline: 1.4817x; 1.4330x over previous
//
#include <hip/hip_runtime.h>
#include <hip/hip_bf16.h>
#include <type_traits>

#define B_   4
#define C_   512
#define C8_  64
#define HW_  4096

typedef short bf16x8 __attribute__((ext_vector_type(8)));
typedef float f32x4  __attribute__((ext_vector_type(4)));

__device__ __forceinline__ unsigned short f2bf(float f) {
  union { unsigned int i; float f; } x; x.f = f;
  unsigned int r = x.i + 0x7fffu + ((x.i >> 16) & 1u);   // RNE
  return (unsigned short)(r >> 16);
}

#define MFMA(a, b, c) __builtin_amdgcn_mfma_f32_16x16x32_bf16((a), (b), (c), 0, 0, 0)

// ---------------------------------------------------------------------------
// Fragment-major workspace layouts (R8): every flash global load becomes one
// fully-contiguous 1KB wave load (lane*16B), replacing 16-row x 64B scatters
// that were saturating per-CU VMEM request throughput.
//
//  Q/K (64-col):  idx = (b*512 + (row>>4)*2 + (col>>5))*512
//                     + ((col>>3)&3)*128 + (row&15)*8 + (col&7)
//     flash reads frag (rowtile, colhalf) at block*512 + lane*8, lane=quad*16+ln
//  V ([ch][m]):   idx = ((b*32 + (ch>>4))*128 + (m>>5))*512
//                     + ((m>>3)&3)*128 + (ch&15)*8 + (m&7)
// ---------------------------------------------------------------------------

// ---------------------------------------------------------------------------
// proj: one dispatch for all three projections.
//   y==0: Qhat = Wq.total + bq            (fragment-major)
//   y==1: Khat = Wk.fe + bk + ht + wt     (pos folded into K, fragment-major)
//   y>=2: Vhat = Wv.fe + bv, ch-chunk (y-2)*128  (fragment-major)
// grid (64, 6, 4), 256 thr.
// ---------------------------------------------------------------------------
__global__ __launch_bounds__(256) void proj_kernel(
    const float* __restrict__ total, const float* __restrict__ fe,
    const float* __restrict__ Wq, const float* __restrict__ bq,
    const float* __restrict__ Wk, const float* __restrict__ bk,
    const float* __restrict__ Wv, const float* __restrict__ bv,
    const float* __restrict__ ht, const float* __restrict__ wt,
    unsigned short* __restrict__ Qh, unsigned short* __restrict__ Kh,
    unsigned short* __restrict__ Vn) {
  __shared__ __align__(16) unsigned short Xs[64 * 72];    // [m][c]
  __shared__ __align__(16) unsigned short Ws[128 * 72];   // [o][c]
  const int t = threadIdx.x;
  const int b = blockIdx.z;
  const int y = blockIdx.y;
  const int x = blockIdx.x;
  const int m0 = x * 64;
  const int lane = t & 63, w = t >> 6, ln = lane & 15, quad = lane >> 4;

  if (y < 2) {
    // ---------------- Q or K ----------------
    const float* X = (y == 0) ? total : fe;
    const float* W = (y == 0) ? Wq : Wk;
    const float* bias = (y == 0) ? bq : bk;
    unsigned short* dst = (y == 0) ? Qh : Kh;

    f32x4 acc[4];
#pragma unroll
    for (int i = 0; i < 4; ++i) acc[i] = f32x4{0.f, 0.f, 0.f, 0.f};

    for (int kb = 0; kb < 8; ++kb) {
      const int c0 = kb * 64;
#pragma unroll
      for (int i = 0; i < 4; ++i) {        // Ws: 64o x 64c
        int idx = t + i * 256; int o = idx >> 4, c4 = idx & 15;
        float4 wv = *(const float4*)&W[(size_t)o * C_ + c0 + c4 * 4];
        unsigned int p0 = f2bf(wv.x) | ((unsigned int)f2bf(wv.y) << 16);
        unsigned int p1 = f2bf(wv.z) | ((unsigned int)f2bf(wv.w) << 16);
        *(uint2*)&Ws[o * 72 + c4 * 4] = make_uint2(p0, p1);
      }
#pragma unroll
      for (int i = 0; i < 4; ++i) {        // Xs: transpose [c][m] -> [m][c]
        int idx = t + i * 256; int rc = idx >> 4, mq = idx & 15;
        float4 xv = *(const float4*)&X[((size_t)b * C_ + c0 + rc) * HW_ + m0 + mq * 4];
        Xs[(mq * 4 + 0) * 72 + rc] = f2bf(xv.x);
        Xs[(mq * 4 + 1) * 72 + rc] = f2bf(xv.y);
        Xs[(mq * 4 + 2) * 72 + rc] = f2bf(xv.z);
        Xs[(mq * 4 + 3) * 72 + rc] = f2bf(xv.w);
      }
      __syncthreads();
      bf16x8 a0 = *(const bf16x8*)&Xs[(w * 16 + ln) * 72 + quad * 8];
      bf16x8 a1 = *(const bf16x8*)&Xs[(w * 16 + ln) * 72 + 32 + quad * 8];
#pragma unroll
      for (int nt = 0; nt < 4; ++nt) {
        bf16x8 b0 = *(const bf16x8*)&Ws[(nt * 16 + ln) * 72 + quad * 8];
        bf16x8 b1 = *(const bf16x8*)&Ws[(nt * 16 + ln) * 72 + 32 + quad * 8];
        acc[nt] = MFMA(a0, b0, acc[nt]);
        acc[nt] = MFMA(a1, b1, acc[nt]);
      }
      __syncthreads();
    }

    const int h = x;  // m-tile of 64 == one image row
#pragma unroll
    for (int nt = 0; nt < 4; ++nt) {
      const int o = nt * 16 + ln;
      const float bz = bias[o];
      const float hv = (y == 1) ? ht[o * 64 + h] : 0.0f;
#pragma unroll
      for (int r = 0; r < 4; ++r) {
        const int mloc = w * 16 + quad * 4 + r;           // m = m0 + mloc
        float val = acc[nt][r] + bz + hv;
        if (y == 1) val += wt[o * 64 + mloc];
        // fragment-major store: row m = m0+mloc, col o
        const size_t idx = ((size_t)b * 512 + (size_t)(x * 4 + w) * 2 + (nt >> 1)) * 512
                         + ((nt & 1) * 2 + (ln >> 3)) * 128 + (quad * 4 + r) * 8 + (ln & 7);
        dst[idx] = f2bf(val);
      }
    }
  } else {
    // ---------------- V chunk ----------------
    const int o0 = (y - 2) * 128;
    f32x4 acc[2][4];
#pragma unroll
    for (int p = 0; p < 2; ++p)
#pragma unroll
      for (int i = 0; i < 4; ++i) acc[p][i] = f32x4{0.f, 0.f, 0.f, 0.f};

    for (int kb = 0; kb < 8; ++kb) {
      const int c0 = kb * 64;
#pragma unroll
      for (int i = 0; i < 8; ++i) {        // Ws: 128o x 64c
        int idx = t + i * 256; int o = idx >> 4, c4 = idx & 15;
        float4 wv = *(const float4*)&Wv[(size_t)(o0 + o) * C_ + c0 + c4 * 4];
        unsigned int p0 = f2bf(wv.x) | ((unsigned int)f2bf(wv.y) << 16);
        unsigned int p1 = f2bf(wv.z) | ((unsigned int)f2bf(wv.w) << 16);
        *(uint2*)&Ws[o * 72 + c4 * 4] = make_uint2(p0, p1);
      }
#pragma unroll
      for (int i = 0; i < 4; ++i) {        // Xs transpose
        int idx = t + i * 256; int rc = idx >> 4, mq = idx & 15;
        float4 xv = *(const float4*)&fe[((size_t)b * C_ + c0 + rc) * HW_ + m0 + mq * 4];
        Xs[(mq * 4 + 0) * 72 + rc] = f2bf(xv.x);
        Xs[(mq * 4 + 1) * 72 + rc] = f2bf(xv.y);
        Xs[(mq * 4 + 2) * 72 + rc] = f2bf(xv.z);
        Xs[(mq * 4 + 3) * 72 + rc] = f2bf(xv.w);
      }
      __syncthreads();
      bf16x8 aW[2][2];
#pragma unroll
      for (int p = 0; p < 2; ++p) {
        aW[p][0] = *(const bf16x8*)&Ws[((w + 4 * p) * 16 + ln) * 72 + quad * 8];
        aW[p][1] = *(const bf16x8*)&Ws[((w + 4 * p) * 16 + ln) * 72 + 32 + quad * 8];
      }
#pragma unroll
      for (int nt = 0; nt < 4; ++nt) {
        bf16x8 b0 = *(const bf16x8*)&Xs[(nt * 16 + ln) * 72 + quad * 8];
        bf16x8 b1 = *(const bf16x8*)&Xs[(nt * 16 + ln) * 72 + 32 + quad * 8];
#pragma unroll
        for (int p = 0; p < 2; ++p) {
          acc[p][nt] = MFMA(aW[p][0], b0, acc[p][nt]);
          acc[p][nt] = MFMA(aW[p][1], b1, acc[p][nt]);
        }
      }
      __syncthreads();
    }

#pragma unroll
    for (int p = 0; p < 2; ++p) {
#pragma unroll
      for (int r = 0; r < 4; ++r) {
        const int cht = (o0 >> 4) + w + 4 * p;            // ch = cht*16 + quad*4+r
        const float bz = bv[cht * 16 + quad * 4 + r];
#pragma unroll
        for (int nt = 0; nt < 4; ++nt) {
          // fragment-major store: ch row, m = m0 + nt*16 + ln
          const size_t idx = (((size_t)b * 32 + cht) * 128 + (size_t)x * 2 + (nt >> 1)) * 512
                           + ((nt & 1) * 2 + (ln >> 3)) * 128 + (quad * 4 + r) * 8 + (ln & 7);
          Vn[idx] = f2bf(acc[p][nt][r] + bz);
        }
      }
    }
  }
}

// ---------------------------------------------------------------------------
// flash R7->R8: identical schedule/LDS/barriers to R7; ONLY the global access
// pattern changed. Q/K/V are now fragment-major, so every kf/vf/aq load is one
// contiguous 1KB wave load (lane*16B) instead of a 16-row x 64B gather.
// Theory: R6->R7 showed per-CU-throughput bound insensitive to wave count;
// the saturated resource is VMEM request/address throughput on the scattered
// fragment gathers (2048 x 64B scattered requests per CU-iteration).
// + s_setprio(1) around MFMA clusters (T5).
// grid (512), 512 thr.
// ---------------------------------------------------------------------------
__global__ __launch_bounds__(512, 4) void flash_kernel(
    const unsigned short* __restrict__ Qh, const unsigned short* __restrict__ Kh,
    const unsigned short* __restrict__ Vn, const float* __restrict__ fe,
    const float* __restrict__ gamma, float* __restrict__ out) {
  __shared__ __align__(16) unsigned short Ps[2][64 * 72];    // 18.4 KB
  __shared__ float Red[2][64];

  const int t = threadIdx.x;
  const int n = blockIdx.x;
  const int xcd = n & 7;                 // XCD swizzle: one (b, half) per XCD
  const int b = xcd & 3;
  const int ch0 = (xcd >> 2) * 256;
  const int q0 = (n >> 3) * 64;
  const int lane = t & 63, w = t >> 6, ln = lane & 15, quad = lane >> 4;
  const int qt = w & 3;                  // q sub-tile (16 rows) for QK^T
  const int kh = w >> 2;                 // k half (32 kpos) for QK^T

  const unsigned short* Qb = Qh + (size_t)b * 512 * 512;
  const unsigned short* Kb = Kh + (size_t)b * 512 * 512;
  // this block's V panel: ch tiles (ch0>>4) .. +15
  const unsigned short* Vbase = Vn + ((size_t)b * 32 + (ch0 >> 4)) * (128 * 512);

  // Q A-fragments: contiguous 1KB wave loads
  const bf16x8 aq0 = *(const bf16x8*)&Qb[((size_t)((q0 >> 4) + qt) * 2 + 0) * 512 + lane * 8];
  const bf16x8 aq1 = *(const bf16x8*)&Qb[((size_t)((q0 >> 4) + qt) * 2 + 1) * 512 + lane * 8];

  float Sacc[4] = {0.f, 0.f, 0.f, 0.f};
  f32x4 acc[2][4];
#pragma unroll
  for (int mt = 0; mt < 2; ++mt)
#pragma unroll
    for (int nt = 0; nt < 4; ++nt) acc[mt][nt] = f32x4{0.f, 0.f, 0.f, 0.f};

  bf16x8 kf[2][2];   // [nt_k][c-half], this wave's kh half only
  bf16x8 vf[2][2];   // [mt][kc], ch rows w*32 + mt*16 + ln

  auto loadK = [&](int it) {
#pragma unroll
    for (int nt = 0; nt < 2; ++nt)
#pragma unroll
      for (int hf = 0; hf < 2; ++hf)
        kf[nt][hf] = *(const bf16x8*)&Kb[((size_t)(it * 4 + kh * 2 + nt) * 2 + hf) * 512 + lane * 8];
  };
  auto loadV = [&](int it) {
#pragma unroll
    for (int mt = 0; mt < 2; ++mt)
#pragma unroll
      for (int kc = 0; kc < 2; ++kc)
        vf[mt][kc] = *(const bf16x8*)&Vbase[(((size_t)(w * 2 + mt)) * 128 + it * 2 + kc) * 512 + lane * 8];
  };

  loadK(0);
  loadV(0);

  for (int it = 0; it < 64; ++it) {      // 64 kpos per iteration
    unsigned short* Pcur = Ps[it & 1];
    // QK^T for this wave's (qt, kh): 16 q rows x 32 kpos
    __builtin_amdgcn_s_setprio(1);
    f32x4 e0 = MFMA(aq0, kf[0][0], (f32x4{0.f, 0.f, 0.f, 0.f}));
    e0 = MFMA(aq1, kf[0][1], e0);
    f32x4 e1 = MFMA(aq0, kf[1][0], (f32x4{0.f, 0.f, 0.f, 0.f}));
    e1 = MFMA(aq1, kf[1][1], e1);
    __builtin_amdgcn_s_setprio(0);
    // K prefetch for it+1 (kf dead after the 4 MFMAs above); stays in
    // flight across the raw barrier.
    if (it < 63) loadK(it + 1);
    // softmax numerators (fixed shift) + inline S accumulation + P stores
#pragma unroll
    for (int r = 0; r < 4; ++r) {
      const float p0 = __expf(e0[r] - 20.0f);
      const float p1 = __expf(e1[r] - 20.0f);
      Sacc[r] += p0 + p1;
      const int qrow = qt * 16 + quad * 4 + r;
      Pcur[qrow * 72 + kh * 32 + ln] = f2bf(p0);
      Pcur[qrow * 72 + kh * 32 + 16 + ln] = f2bf(p1);
    }
    // P stores visible to all waves; do NOT drain vmcnt (prefetches in flight)
    asm volatile("s_waitcnt lgkmcnt(0)" ::: "memory");
    __builtin_amdgcn_s_barrier();
    asm volatile("" ::: "memory");
    // PV: D[ch][q] over 64 kpos in two 32-k chunks
#pragma unroll
    for (int kc = 0; kc < 2; ++kc) {
      bf16x8 bp[4];
#pragma unroll
      for (int nt = 0; nt < 4; ++nt)
        bp[nt] = *(const bf16x8*)&Pcur[(nt * 16 + ln) * 72 + kc * 32 + quad * 8];
      __builtin_amdgcn_s_setprio(1);
#pragma unroll
      for (int mt = 0; mt < 2; ++mt)
#pragma unroll
        for (int nt = 0; nt < 4; ++nt)
          acc[mt][nt] = MFMA(vf[mt][kc], bp[nt], acc[mt][nt]);
      __builtin_amdgcn_s_setprio(0);
    }
    // V prefetch for it+1 (vf dead after PV)
    if (it < 63) loadV(it + 1);
  }

  // ---- S reduce (per kh half, summed at read) + epilogue ----
#pragma unroll
  for (int r = 0; r < 4; ++r) {
    float s = Sacc[r];
    s += __shfl_xor(s, 1, 16);
    s += __shfl_xor(s, 2, 16);
    s += __shfl_xor(s, 4, 16);
    s += __shfl_xor(s, 8, 16);
    if (ln == 0) Red[kh][qt * 16 + quad * 4 + r] = s;
  }
  __syncthreads();
  float rsv[4];
#pragma unroll
  for (int nt = 0; nt < 4; ++nt)
    rsv[nt] = 1.0f / (Red[0][nt * 16 + ln] + Red[1][nt * 16 + ln]);

  const float g = gamma[0];
#pragma unroll
  for (int mt = 0; mt < 2; ++mt) {
#pragma unroll
    for (int r = 0; r < 4; ++r) {
      const int ch = ch0 + w * 32 + mt * 16 + quad * 4 + r;
      const size_t base = ((size_t)b * C_ + ch) * HW_ + q0;
#pragma unroll
      for (int nt = 0; nt < 4; ++nt) {
        const size_t idx = base + nt * 16 + ln;
        out[idx] = g * (acc[mt][nt][r] * rsv[nt]) + fe[idx];
      }
    }
  }
}

// ---------------------------------------------------------------------------
extern "C" void kernel_launch(void* const* d_in, const int* in_sizes, int n_in,
                              void* d_out, int out_size, void* d_ws, size_t ws_size,
                              hipStream_t stream) {
  const float* fe    = (const float*)d_in[0];
  const float* total = (const float*)d_in[1];
  const float* Wq    = (const float*)d_in[2];
  const float* bq    = (const float*)d_in[3];
  const float* Wk    = (const float*)d_in[4];
  const float* bk    = (const float*)d_in[5];
  const float* Wv    = (const float*)d_in[6];
  const float* bv    = (const float*)d_in[7];
  const float* ht    = (const float*)d_in[8];
  const float* wt    = (const float*)d_in[9];
  const float* gamma = (const float*)d_in[10];
  float* out = (float*)d_out;

  // ws: Qhat 2MB | Khat 2MB | Vhat 16MB (fragment-major)
  unsigned short* Qh = (unsigned short*)d_ws;
  unsigned short* Kh = Qh + (size_t)B_ * HW_ * C8_;
  unsigned short* Vn = Kh + (size_t)B_ * HW_ * C8_;

  proj_kernel<<<dim3(64, 6, B_), 256, 0, stream>>>(total, fe, Wq, bq, Wk, bk,
                                                   Wv, bv, ht, wt, Qh, Kh, Vn);
  flash_kernel<<<dim3(512), 512, 0, stream>>>(Qh, Kh, Vn, fe, gamma, out);
}

// Round 3
// 262.923 us; speedup vs baseline: 1.5288x; 1.0318x over previous
//
#include <hip/hip_runtime.h>
#include <hip/hip_bf16.h>
#include <type_traits>

#define B_   4
#define C_   512
#define C8_  64
#define HW_  4096

typedef short bf16x8 __attribute__((ext_vector_type(8)));
typedef float f32x4  __attribute__((ext_vector_type(4)));

__device__ __forceinline__ unsigned short f2bf(float f) {
  union { unsigned int i; float f; } x; x.f = f;
  unsigned int r = x.i + 0x7fffu + ((x.i >> 16) & 1u);   // RNE
  return (unsigned short)(r >> 16);
}

// packed f32x2 -> bf16x2 (RNE), single VALU op; no builtin on gfx950
__device__ __forceinline__ unsigned int cvtpk(float lo, float hi) {
  unsigned int r;
  asm("v_cvt_pk_bf16_f32 %0, %1, %2" : "=v"(r) : "v"(lo), "v"(hi));
  return r;
}

#define MFMA(a, b, c) __builtin_amdgcn_mfma_f32_16x16x32_bf16((a), (b), (c), 0, 0, 0)

// ---------------------------------------------------------------------------
// Fragment-major workspace layouts (R8): every flash global load is one
// fully-contiguous 1KB wave load (lane*16B).
//  Q/K (64-col):  idx = (b*512 + (row>>4)*2 + (col>>5))*512
//                     + ((col>>3)&3)*128 + (row&15)*8 + (col&7)
//  V ([ch][m]):   idx = ((b*32 + (ch>>4))*128 + (m>>5))*512
//                     + ((m>>3)&3)*128 + (ch&15)*8 + (m&7)
// ---------------------------------------------------------------------------

// ---------------------------------------------------------------------------
// proj: one dispatch for all three projections (unchanged from R8).
// grid (64, 6, 4), 256 thr.
// ---------------------------------------------------------------------------
__global__ __launch_bounds__(256) void proj_kernel(
    const float* __restrict__ total, const float* __restrict__ fe,
    const float* __restrict__ Wq, const float* __restrict__ bq,
    const float* __restrict__ Wk, const float* __restrict__ bk,
    const float* __restrict__ Wv, const float* __restrict__ bv,
    const float* __restrict__ ht, const float* __restrict__ wt,
    unsigned short* __restrict__ Qh, unsigned short* __restrict__ Kh,
    unsigned short* __restrict__ Vn) {
  __shared__ __align__(16) unsigned short Xs[64 * 72];    // [m][c]
  __shared__ __align__(16) unsigned short Ws[128 * 72];   // [o][c]
  const int t = threadIdx.x;
  const int b = blockIdx.z;
  const int y = blockIdx.y;
  const int x = blockIdx.x;
  const int m0 = x * 64;
  const int lane = t & 63, w = t >> 6, ln = lane & 15, quad = lane >> 4;

  if (y < 2) {
    // ---------------- Q or K ----------------
    const float* X = (y == 0) ? total : fe;
    const float* W = (y == 0) ? Wq : Wk;
    const float* bias = (y == 0) ? bq : bk;
    unsigned short* dst = (y == 0) ? Qh : Kh;

    f32x4 acc[4];
#pragma unroll
    for (int i = 0; i < 4; ++i) acc[i] = f32x4{0.f, 0.f, 0.f, 0.f};

    for (int kb = 0; kb < 8; ++kb) {
      const int c0 = kb * 64;
#pragma unroll
      for (int i = 0; i < 4; ++i) {        // Ws: 64o x 64c
        int idx = t + i * 256; int o = idx >> 4, c4 = idx & 15;
        float4 wv = *(const float4*)&W[(size_t)o * C_ + c0 + c4 * 4];
        unsigned int p0 = f2bf(wv.x) | ((unsigned int)f2bf(wv.y) << 16);
        unsigned int p1 = f2bf(wv.z) | ((unsigned int)f2bf(wv.w) << 16);
        *(uint2*)&Ws[o * 72 + c4 * 4] = make_uint2(p0, p1);
      }
#pragma unroll
      for (int i = 0; i < 4; ++i) {        // Xs: transpose [c][m] -> [m][c]
        int idx = t + i * 256; int rc = idx >> 4, mq = idx & 15;
        float4 xv = *(const float4*)&X[((size_t)b * C_ + c0 + rc) * HW_ + m0 + mq * 4];
        Xs[(mq * 4 + 0) * 72 + rc] = f2bf(xv.x);
        Xs[(mq * 4 + 1) * 72 + rc] = f2bf(xv.y);
        Xs[(mq * 4 + 2) * 72 + rc] = f2bf(xv.z);
        Xs[(mq * 4 + 3) * 72 + rc] = f2bf(xv.w);
      }
      __syncthreads();
      bf16x8 a0 = *(const bf16x8*)&Xs[(w * 16 + ln) * 72 + quad * 8];
      bf16x8 a1 = *(const bf16x8*)&Xs[(w * 16 + ln) * 72 + 32 + quad * 8];
#pragma unroll
      for (int nt = 0; nt < 4; ++nt) {
        bf16x8 b0 = *(const bf16x8*)&Ws[(nt * 16 + ln) * 72 + quad * 8];
        bf16x8 b1 = *(const bf16x8*)&Ws[(nt * 16 + ln) * 72 + 32 + quad * 8];
        acc[nt] = MFMA(a0, b0, acc[nt]);
        acc[nt] = MFMA(a1, b1, acc[nt]);
      }
      __syncthreads();
    }

    const int h = x;  // m-tile of 64 == one image row
#pragma unroll
    for (int nt = 0; nt < 4; ++nt) {
      const int o = nt * 16 + ln;
      const float bz = bias[o];
      const float hv = (y == 1) ? ht[o * 64 + h] : 0.0f;
#pragma unroll
      for (int r = 0; r < 4; ++r) {
        const int mloc = w * 16 + quad * 4 + r;           // m = m0 + mloc
        float val = acc[nt][r] + bz + hv;
        if (y == 1) val += wt[o * 64 + mloc];
        // fragment-major store: row m = m0+mloc, col o
        const size_t idx = ((size_t)b * 512 + (size_t)(x * 4 + w) * 2 + (nt >> 1)) * 512
                         + ((nt & 1) * 2 + (ln >> 3)) * 128 + (quad * 4 + r) * 8 + (ln & 7);
        dst[idx] = f2bf(val);
      }
    }
  } else {
    // ---------------- V chunk ----------------
    const int o0 = (y - 2) * 128;
    f32x4 acc[2][4];
#pragma unroll
    for (int p = 0; p < 2; ++p)
#pragma unroll
      for (int i = 0; i < 4; ++i) acc[p][i] = f32x4{0.f, 0.f, 0.f, 0.f};

    for (int kb = 0; kb < 8; ++kb) {
      const int c0 = kb * 64;
#pragma unroll
      for (int i = 0; i < 8; ++i) {        // Ws: 128o x 64c
        int idx = t + i * 256; int o = idx >> 4, c4 = idx & 15;
        float4 wv = *(const float4*)&Wv[(size_t)(o0 + o) * C_ + c0 + c4 * 4];
        unsigned int p0 = f2bf(wv.x) | ((unsigned int)f2bf(wv.y) << 16);
        unsigned int p1 = f2bf(wv.z) | ((unsigned int)f2bf(wv.w) << 16);
        *(uint2*)&Ws[o * 72 + c4 * 4] = make_uint2(p0, p1);
      }
#pragma unroll
      for (int i = 0; i < 4; ++i) {        // Xs transpose
        int idx = t + i * 256; int rc = idx >> 4, mq = idx & 15;
        float4 xv = *(const float4*)&fe[((size_t)b * C_ + c0 + rc) * HW_ + m0 + mq * 4];
        Xs[(mq * 4 + 0) * 72 + rc] = f2bf(xv.x);
        Xs[(mq * 4 + 1) * 72 + rc] = f2bf(xv.y);
        Xs[(mq * 4 + 2) * 72 + rc] = f2bf(xv.z);
        Xs[(mq * 4 + 3) * 72 + rc] = f2bf(xv.w);
      }
      __syncthreads();
      bf16x8 aW[2][2];
#pragma unroll
      for (int p = 0; p < 2; ++p) {
        aW[p][0] = *(const bf16x8*)&Ws[((w + 4 * p) * 16 + ln) * 72 + quad * 8];
        aW[p][1] = *(const bf16x8*)&Ws[((w + 4 * p) * 16 + ln) * 72 + 32 + quad * 8];
      }
#pragma unroll
      for (int nt = 0; nt < 4; ++nt) {
        bf16x8 b0 = *(const bf16x8*)&Xs[(nt * 16 + ln) * 72 + quad * 8];
        bf16x8 b1 = *(const bf16x8*)&Xs[(nt * 16 + ln) * 72 + 32 + quad * 8];
#pragma unroll
        for (int p = 0; p < 2; ++p) {
          acc[p][nt] = MFMA(aW[p][0], b0, acc[p][nt]);
          acc[p][nt] = MFMA(aW[p][1], b1, acc[p][nt]);
        }
      }
      __syncthreads();
    }

#pragma unroll
    for (int p = 0; p < 2; ++p) {
#pragma unroll
      for (int r = 0; r < 4; ++r) {
        const int cht = (o0 >> 4) + w + 4 * p;            // ch = cht*16 + quad*4+r
        const float bz = bv[cht * 16 + quad * 4 + r];
#pragma unroll
        for (int nt = 0; nt < 4; ++nt) {
          // fragment-major store: ch row, m = m0 + nt*16 + ln
          const size_t idx = (((size_t)b * 32 + cht) * 128 + (size_t)x * 2 + (nt >> 1)) * 512
                           + ((nt & 1) * 2 + (ln >> 3)) * 128 + (quad * 4 + r) * 8 + (ln & 7);
          Vn[idx] = f2bf(acc[p][nt][r] + bz);
        }
      }
    }
  }
}

// ---------------------------------------------------------------------------
// flash R8->R9: swapped QK^T + packed P path.
//   E = mfma(K, Q) (operands swapped) -> lane holds E[k=quad*4+r][q=ln]:
//   adjacent-k per lane, so P->bf16 is 4 v_cvt_pk_bf16_f32 + 2 ds_write_b64
//   per wave-iter (was 8 f2bf chains ~40 VALU + 16 scattered ds_write_b16).
//   P tile now [64q][64k] row-major (128B rows) with XOR swizzle
//   byte ^= (q&7)<<4: b64 writes 2-way (free), b128 reads 8 start banks.
//   S-reduce: lane owns one q column -> 2 shfl_xor (16,32) instead of 16.
// Same schedule: 8 waves (qt=w&3, kh=w>>2), 1 raw barrier/iter (lgkm only),
// K/V reg prefetch in flight across barrier. grid (512), 512 thr.
// ---------------------------------------------------------------------------
__global__ __launch_bounds__(512, 4) void flash_kernel(
    const unsigned short* __restrict__ Qh, const unsigned short* __restrict__ Kh,
    const unsigned short* __restrict__ Vn, const float* __restrict__ fe,
    const float* __restrict__ gamma, float* __restrict__ out) {
  __shared__ __align__(16) unsigned short Ps[2][64 * 64];    // 16 KB, swizzled
  __shared__ float Red[2][64];

  const int t = threadIdx.x;
  const int n = blockIdx.x;
  const int xcd = n & 7;                 // XCD swizzle: one (b, half) per XCD
  const int b = xcd & 3;
  const int ch0 = (xcd >> 2) * 256;
  const int q0 = (n >> 3) * 64;
  const int lane = t & 63, w = t >> 6, ln = lane & 15, quad = lane >> 4;
  const int qt = w & 3;                  // q sub-tile (16 rows) for QK^T
  const int kh = w >> 2;                 // k half (32 kpos) for QK^T
  const int swz = (ln & 7) << 4;         // P LDS XOR swizzle (byte)

  const unsigned short* Qb = Qh + (size_t)b * 512 * 512;
  const unsigned short* Kb = Kh + (size_t)b * 512 * 512;
  const unsigned short* Vbase = Vn + ((size_t)b * 32 + (ch0 >> 4)) * (128 * 512);

  // Q B-fragments: contiguous 1KB wave loads
  const bf16x8 aq0 = *(const bf16x8*)&Qb[((size_t)((q0 >> 4) + qt) * 2 + 0) * 512 + lane * 8];
  const bf16x8 aq1 = *(const bf16x8*)&Qb[((size_t)((q0 >> 4) + qt) * 2 + 1) * 512 + lane * 8];

  float Sacc = 0.f;                      // partial softmax denom for q=qt*16+ln
  f32x4 acc[2][4];
#pragma unroll
  for (int mt = 0; mt < 2; ++mt)
#pragma unroll
    for (int nt = 0; nt < 4; ++nt) acc[mt][nt] = f32x4{0.f, 0.f, 0.f, 0.f};

  bf16x8 kf[2][2];   // [nt_k][c-half], this wave's kh half only
  bf16x8 vf[2][2];   // [mt][kc], ch rows w*32 + mt*16 + ln

  auto loadK = [&](int it) {
#pragma unroll
    for (int nt = 0; nt < 2; ++nt)
#pragma unroll
      for (int hf = 0; hf < 2; ++hf)
        kf[nt][hf] = *(const bf16x8*)&Kb[((size_t)(it * 4 + kh * 2 + nt) * 2 + hf) * 512 + lane * 8];
  };
  auto loadV = [&](int it) {
#pragma unroll
    for (int mt = 0; mt < 2; ++mt)
#pragma unroll
      for (int kc = 0; kc < 2; ++kc)
        vf[mt][kc] = *(const bf16x8*)&Vbase[(((size_t)(w * 2 + mt)) * 128 + it * 2 + kc) * 512 + lane * 8];
  };

  loadK(0);
  loadV(0);

  const int qrow = qt * 16 + ln;         // this lane's q column in E

  for (int it = 0; it < 64; ++it) {      // 64 kpos per iteration
    char* Pcur = (char*)Ps[it & 1];
    // swapped QK^T: E[k][q] for this wave's (kh, qt)
    __builtin_amdgcn_s_setprio(1);
    f32x4 e0 = MFMA(kf[0][0], aq0, (f32x4{0.f, 0.f, 0.f, 0.f}));
    e0 = MFMA(kf[0][1], aq1, e0);
    f32x4 e1 = MFMA(kf[1][0], aq0, (f32x4{0.f, 0.f, 0.f, 0.f}));
    e1 = MFMA(kf[1][1], aq1, e1);
    __builtin_amdgcn_s_setprio(0);
    // K prefetch for it+1 (kf dead); stays in flight across the barrier.
    if (it < 63) loadK(it + 1);
    // softmax numerators (fixed shift exp(E-20)), packed bf16 store + S acc
    {
      const float p0 = __expf(e0[0] - 20.0f), p1 = __expf(e0[1] - 20.0f);
      const float p2 = __expf(e0[2] - 20.0f), p3 = __expf(e0[3] - 20.0f);
      Sacc += (p0 + p1) + (p2 + p3);
      *(uint2*)(Pcur + ((qrow * 128 + kh * 64 + 0 * 32 + quad * 8) ^ swz)) =
          make_uint2(cvtpk(p0, p1), cvtpk(p2, p3));
      const float s0 = __expf(e1[0] - 20.0f), s1 = __expf(e1[1] - 20.0f);
      const float s2 = __expf(e1[2] - 20.0f), s3 = __expf(e1[3] - 20.0f);
      Sacc += (s0 + s1) + (s2 + s3);
      *(uint2*)(Pcur + ((qrow * 128 + kh * 64 + 1 * 32 + quad * 8) ^ swz)) =
          make_uint2(cvtpk(s0, s1), cvtpk(s2, s3));
    }
    // P stores visible to all waves; do NOT drain vmcnt (prefetches in flight)
    asm volatile("s_waitcnt lgkmcnt(0)" ::: "memory");
    __builtin_amdgcn_s_barrier();
    asm volatile("" ::: "memory");
    // PV: D[ch][q] over 64 kpos in two 32-k chunks
#pragma unroll
    for (int kc = 0; kc < 2; ++kc) {
      bf16x8 bp[4];
#pragma unroll
      for (int nt = 0; nt < 4; ++nt)
        bp[nt] = *(const bf16x8*)(Pcur + ((((nt * 16 + ln) * 128 + kc * 64 + quad * 16)) ^ swz));
      __builtin_amdgcn_s_setprio(1);
#pragma unroll
      for (int mt = 0; mt < 2; ++mt)
#pragma unroll
        for (int nt = 0; nt < 4; ++nt)
          acc[mt][nt] = MFMA(vf[mt][kc], bp[nt], acc[mt][nt]);
      __builtin_amdgcn_s_setprio(0);
    }
    // V prefetch for it+1 (vf dead after PV)
    if (it < 63) loadV(it + 1);
  }

  // ---- S reduce (sum over quads = this wave's k range) + epilogue ----
  {
    float s = Sacc;
    s += __shfl_xor(s, 16);
    s += __shfl_xor(s, 32);
    if (quad == 0) Red[kh][qrow] = s;
  }
  __syncthreads();
  float rsv[4];
#pragma unroll
  for (int nt = 0; nt < 4; ++nt)
    rsv[nt] = 1.0f / (Red[0][nt * 16 + ln] + Red[1][nt * 16 + ln]);

  const float g = gamma[0];
#pragma unroll
  for (int mt = 0; mt < 2; ++mt) {
#pragma unroll
    for (int r = 0; r < 4; ++r) {
      const int ch = ch0 + w * 32 + mt * 16 + quad * 4 + r;
      const size_t base = ((size_t)b * C_ + ch) * HW_ + q0;
#pragma unroll
      for (int nt = 0; nt < 4; ++nt) {
        const size_t idx = base + nt * 16 + ln;
        out[idx] = g * (acc[mt][nt][r] * rsv[nt]) + fe[idx];
      }
    }
  }
}

// ---------------------------------------------------------------------------
extern "C" void kernel_launch(void* const* d_in, const int* in_sizes, int n_in,
                              void* d_out, int out_size, void* d_ws, size_t ws_size,
                              hipStream_t stream) {
  const float* fe    = (const float*)d_in[0];
  const float* total = (const float*)d_in[1];
  const float* Wq    = (const float*)d_in[2];
  const float* bq    = (const float*)d_in[3];
  const float* Wk    = (const float*)d_in[4];
  const float* bk    = (const float*)d_in[5];
  const float* Wv    = (const float*)d_in[6];
  const float* bv    = (const float*)d_in[7];
  const float* ht    = (const float*)d_in[8];
  const float* wt    = (const float*)d_in[9];
  const float* gamma = (const float*)d_in[10];
  float* out = (float*)d_out;

  // ws: Qhat 2MB | Khat 2MB | Vhat 16MB (fragment-major)
  unsigned short* Qh = (unsigned short*)d_ws;
  unsigned short* Kh = Qh + (size_t)B_ * HW_ * C8_;
  unsigned short* Vn = Kh + (size_t)B_ * HW_ * C8_;

  proj_kernel<<<dim3(64, 6, B_), 256, 0, stream>>>(total, fe, Wq, bq, Wk, bk,
                                                   Wv, bv, ht, wt, Qh, Kh, Vn);
  flash_kernel<<<dim3(512), 512, 0, stream>>>(Qh, Kh, Vn, fe, gamma, out);
}

// Round 4
// 228.213 us; speedup vs baseline: 1.7614x; 1.1521x over previous
//
#include <hip/hip_runtime.h>
#include <hip/hip_bf16.h>

#define B_   4
#define C_   512
#define C8_  64
#define HW_  4096

typedef short bf16x8 __attribute__((ext_vector_type(8)));
typedef float f32x4  __attribute__((ext_vector_type(4)));

__device__ __forceinline__ unsigned short f2bf(float f) {
  union { unsigned int i; float f; } x; x.f = f;
  unsigned int r = x.i + 0x7fffu + ((x.i >> 16) & 1u);   // RNE
  return (unsigned short)(r >> 16);
}

// packed f32x2 -> bf16x2 (RNE), single VALU op; no builtin on gfx950
__device__ __forceinline__ unsigned int cvtpk(float lo, float hi) {
  unsigned int r;
  asm("v_cvt_pk_bf16_f32 %0, %1, %2" : "=v"(r) : "v"(lo), "v"(hi));
  return r;
}

// 2^x, single transcendental op (what __ocml exp2 lowers to in-range)
__device__ __forceinline__ float fexp2(float x) {
  float r;
  asm("v_exp_f32 %0, %1" : "=v"(r) : "v"(x));
  return r;
}

#define MFMA(a, b, c) __builtin_amdgcn_mfma_f32_16x16x32_bf16((a), (b), (c), 0, 0, 0)

#define LOG2E 1.44269504f
#define NEG20LOG2E -28.8539008f   // -20*log2(e): folded softmax shift (C-init)

// ---------------------------------------------------------------------------
// Fragment-major workspace layouts (R8): every flash global load is one
// fully-contiguous 1KB wave load (lane*16B).
//  Q/K (64-col):  idx = (b*512 + (row>>4)*2 + (col>>5))*512
//                     + ((col>>3)&3)*128 + (row&15)*8 + (col&7)
//  V ([ch][m]):   idx = ((b*32 + (ch>>4))*128 + (m>>5))*512
//                     + ((m>>3)&3)*128 + (ch&15)*8 + (m&7)
//  Q is pre-scaled by log2e (flash uses v_exp_f32 with C-init -20*log2e).
// ---------------------------------------------------------------------------

// ---------------------------------------------------------------------------
// proj R9->R10: staging fixed.
//  - Xs transpose: 4-c-row loads + cvt_pk + b64 writes (was scalar b16 at a
//    structural 16-way bank conflict + 16 f2bf per thread per kb).
//  - Ws staging: cvt_pk (2 ops) instead of 4 f2bf (~16 ops).
// grid (64, 6, 4), 256 thr.
// ---------------------------------------------------------------------------
__global__ __launch_bounds__(256) void proj_kernel(
    const float* __restrict__ total, const float* __restrict__ fe,
    const float* __restrict__ Wq, const float* __restrict__ bq,
    const float* __restrict__ Wk, const float* __restrict__ bk,
    const float* __restrict__ Wv, const float* __restrict__ bv,
    const float* __restrict__ ht, const float* __restrict__ wt,
    unsigned short* __restrict__ Qh, unsigned short* __restrict__ Kh,
    unsigned short* __restrict__ Vn) {
  __shared__ __align__(16) unsigned short Xs[64 * 72];    // [m][c]
  __shared__ __align__(16) unsigned short Ws[128 * 72];   // [o][c]
  const int t = threadIdx.x;
  const int b = blockIdx.z;
  const int y = blockIdx.y;
  const int x = blockIdx.x;
  const int m0 = x * 64;
  const int lane = t & 63, w = t >> 6, ln = lane & 15, quad = lane >> 4;
  const int rc4 = t >> 4, mq = t & 15;    // Xs staging coords

  if (y < 2) {
    // ---------------- Q or K ----------------
    const float* X = (y == 0) ? total : fe;
    const float* W = (y == 0) ? Wq : Wk;
    const float* bias = (y == 0) ? bq : bk;
    unsigned short* dst = (y == 0) ? Qh : Kh;

    f32x4 acc[4];
#pragma unroll
    for (int i = 0; i < 4; ++i) acc[i] = f32x4{0.f, 0.f, 0.f, 0.f};

    for (int kb = 0; kb < 8; ++kb) {
      const int c0 = kb * 64;
#pragma unroll
      for (int i = 0; i < 4; ++i) {        // Ws: 64o x 64c
        int idx = t + i * 256; int o = idx >> 4, c4 = idx & 15;
        f32x4 wv = *(const f32x4*)&W[(size_t)o * C_ + c0 + c4 * 4];
        *(uint2*)&Ws[o * 72 + c4 * 4] = make_uint2(cvtpk(wv[0], wv[1]), cvtpk(wv[2], wv[3]));
      }
      {                                    // Xs: [c][m] -> [m][c], b64 packed
        f32x4 xv[4];
#pragma unroll
        for (int k = 0; k < 4; ++k)
          xv[k] = *(const f32x4*)&X[((size_t)b * C_ + c0 + rc4 * 4 + k) * HW_ + m0 + mq * 4];
#pragma unroll
        for (int j = 0; j < 4; ++j)
          *(uint2*)&Xs[(mq * 4 + j) * 72 + rc4 * 4] =
              make_uint2(cvtpk(xv[0][j], xv[1][j]), cvtpk(xv[2][j], xv[3][j]));
      }
      __syncthreads();
      bf16x8 a0 = *(const bf16x8*)&Xs[(w * 16 + ln) * 72 + quad * 8];
      bf16x8 a1 = *(const bf16x8*)&Xs[(w * 16 + ln) * 72 + 32 + quad * 8];
#pragma unroll
      for (int nt = 0; nt < 4; ++nt) {
        bf16x8 b0 = *(const bf16x8*)&Ws[(nt * 16 + ln) * 72 + quad * 8];
        bf16x8 b1 = *(const bf16x8*)&Ws[(nt * 16 + ln) * 72 + 32 + quad * 8];
        acc[nt] = MFMA(a0, b0, acc[nt]);
        acc[nt] = MFMA(a1, b1, acc[nt]);
      }
      __syncthreads();
    }

    const int h = x;  // m-tile of 64 == one image row
#pragma unroll
    for (int nt = 0; nt < 4; ++nt) {
      const int o = nt * 16 + ln;
      const float bz = bias[o];
      const float hv = (y == 1) ? ht[o * 64 + h] : 0.0f;
#pragma unroll
      for (int r = 0; r < 4; ++r) {
        const int mloc = w * 16 + quad * 4 + r;           // m = m0 + mloc
        float val = acc[nt][r] + bz + hv;
        if (y == 1) val += wt[o * 64 + mloc];
        if (y == 0) val *= LOG2E;                          // fold exp->exp2
        // fragment-major store: row m = m0+mloc, col o
        const size_t idx = ((size_t)b * 512 + (size_t)(x * 4 + w) * 2 + (nt >> 1)) * 512
                         + ((nt & 1) * 2 + (ln >> 3)) * 128 + (quad * 4 + r) * 8 + (ln & 7);
        dst[idx] = f2bf(val);
      }
    }
  } else {
    // ---------------- V chunk ----------------
    const int o0 = (y - 2) * 128;
    f32x4 acc[2][4];
#pragma unroll
    for (int p = 0; p < 2; ++p)
#pragma unroll
      for (int i = 0; i < 4; ++i) acc[p][i] = f32x4{0.f, 0.f, 0.f, 0.f};

    for (int kb = 0; kb < 8; ++kb) {
      const int c0 = kb * 64;
#pragma unroll
      for (int i = 0; i < 8; ++i) {        // Ws: 128o x 64c
        int idx = t + i * 256; int o = idx >> 4, c4 = idx & 15;
        f32x4 wv = *(const f32x4*)&Wv[(size_t)(o0 + o) * C_ + c0 + c4 * 4];
        *(uint2*)&Ws[o * 72 + c4 * 4] = make_uint2(cvtpk(wv[0], wv[1]), cvtpk(wv[2], wv[3]));
      }
      {                                    // Xs transpose, b64 packed
        f32x4 xv[4];
#pragma unroll
        for (int k = 0; k < 4; ++k)
          xv[k] = *(const f32x4*)&fe[((size_t)b * C_ + c0 + rc4 * 4 + k) * HW_ + m0 + mq * 4];
#pragma unroll
        for (int j = 0; j < 4; ++j)
          *(uint2*)&Xs[(mq * 4 + j) * 72 + rc4 * 4] =
              make_uint2(cvtpk(xv[0][j], xv[1][j]), cvtpk(xv[2][j], xv[3][j]));
      }
      __syncthreads();
      bf16x8 aW[2][2];
#pragma unroll
      for (int p = 0; p < 2; ++p) {
        aW[p][0] = *(const bf16x8*)&Ws[((w + 4 * p) * 16 + ln) * 72 + quad * 8];
        aW[p][1] = *(const bf16x8*)&Ws[((w + 4 * p) * 16 + ln) * 72 + 32 + quad * 8];
      }
#pragma unroll
      for (int nt = 0; nt < 4; ++nt) {
        bf16x8 b0 = *(const bf16x8*)&Xs[(nt * 16 + ln) * 72 + quad * 8];
        bf16x8 b1 = *(const bf16x8*)&Xs[(nt * 16 + ln) * 72 + 32 + quad * 8];
#pragma unroll
        for (int p = 0; p < 2; ++p) {
          acc[p][nt] = MFMA(aW[p][0], b0, acc[p][nt]);
          acc[p][nt] = MFMA(aW[p][1], b1, acc[p][nt]);
        }
      }
      __syncthreads();
    }

#pragma unroll
    for (int p = 0; p < 2; ++p) {
#pragma unroll
      for (int r = 0; r < 4; ++r) {
        const int cht = (o0 >> 4) + w + 4 * p;            // ch = cht*16 + quad*4+r
        const float bz = bv[cht * 16 + quad * 4 + r];
#pragma unroll
        for (int nt = 0; nt < 4; ++nt) {
          // fragment-major store: ch row, m = m0 + nt*16 + ln
          const size_t idx = (((size_t)b * 32 + cht) * 128 + (size_t)x * 2 + (nt >> 1)) * 512
                           + ((nt & 1) * 2 + (ln >> 3)) * 128 + (quad * 4 + r) * 8 + (ln & 7);
          Vn[idx] = f2bf(acc[p][nt][r] + bz);
        }
      }
    }
  }
}

// ---------------------------------------------------------------------------
// flash R9->R10: software-pipelined phase. Per inter-barrier phase:
//   {read P(t) frags || QK(t+1)+exp2+write P(t+1)}  then  PV(t).
// The two chains are independent -> LDS-read latency and PV MFMAs overlap the
// QK/exp/write chain (R9 ran them serially: MfmaUtil 37 / VALU 39 / LDS ~45%,
// nothing saturated = program-order serialization).
// exp: Q pre-scaled by log2e + MFMA C-init = -20*log2e -> bare v_exp_f32.
// Buffer safety (2 bufs, 1 barrier/phase): reads of buf X in phase t complete
// before barrier(t) (lgkmcnt(0) covers them); next writes to X are in phase
// t+1 after barrier(t).
// grid (512), 512 thr.
// ---------------------------------------------------------------------------
__global__ __launch_bounds__(512, 4) void flash_kernel(
    const unsigned short* __restrict__ Qh, const unsigned short* __restrict__ Kh,
    const unsigned short* __restrict__ Vn, const float* __restrict__ fe,
    const float* __restrict__ gamma, float* __restrict__ out) {
  __shared__ __align__(16) unsigned short Ps[2][64 * 64];    // 16 KB, swizzled
  __shared__ float Red[2][64];

  const int t = threadIdx.x;
  const int n = blockIdx.x;
  const int xcd = n & 7;                 // XCD swizzle: one (b, half) per XCD
  const int b = xcd & 3;
  const int ch0 = (xcd >> 2) * 256;
  const int q0 = (n >> 3) * 64;
  const int lane = t & 63, w = t >> 6, ln = lane & 15, quad = lane >> 4;
  const int qt = w & 3;                  // q sub-tile (16 rows) for QK^T
  const int kh = w >> 2;                 // k half (32 kpos) for QK^T
  const int swz = (ln & 7) << 4;         // P LDS XOR swizzle (byte)

  const unsigned short* Qb = Qh + (size_t)b * 512 * 512;
  const unsigned short* Kb = Kh + (size_t)b * 512 * 512;
  const unsigned short* Vbase = Vn + ((size_t)b * 32 + (ch0 >> 4)) * (128 * 512);

  // Q B-fragments (pre-scaled by log2e): contiguous 1KB wave loads
  const bf16x8 aq0 = *(const bf16x8*)&Qb[((size_t)((q0 >> 4) + qt) * 2 + 0) * 512 + lane * 8];
  const bf16x8 aq1 = *(const bf16x8*)&Qb[((size_t)((q0 >> 4) + qt) * 2 + 1) * 512 + lane * 8];

  const f32x4 CINIT = {NEG20LOG2E, NEG20LOG2E, NEG20LOG2E, NEG20LOG2E};

  float Sacc = 0.f;                      // partial softmax denom for q=qt*16+ln
  f32x4 acc[2][4];
#pragma unroll
  for (int mt = 0; mt < 2; ++mt)
#pragma unroll
    for (int nt = 0; nt < 4; ++nt) acc[mt][nt] = f32x4{0.f, 0.f, 0.f, 0.f};

  bf16x8 kf[2][2];   // [nt_k][c-half], this wave's kh half only
  bf16x8 vf[2][2];   // [mt][kc], ch rows w*32 + mt*16 + ln

  auto loadK = [&](int it) {
#pragma unroll
    for (int nt = 0; nt < 2; ++nt)
#pragma unroll
      for (int hf = 0; hf < 2; ++hf)
        kf[nt][hf] = *(const bf16x8*)&Kb[((size_t)(it * 4 + kh * 2 + nt) * 2 + hf) * 512 + lane * 8];
  };
  auto loadV = [&](int it) {
#pragma unroll
    for (int mt = 0; mt < 2; ++mt)
#pragma unroll
      for (int kc = 0; kc < 2; ++kc)
        vf[mt][kc] = *(const bf16x8*)&Vbase[(((size_t)(w * 2 + mt)) * 128 + it * 2 + kc) * 512 + lane * 8];
  };

  const int qrow = qt * 16 + ln;         // this lane's q column in E

  // exp2 + packed bf16 store of one 32k x 16q E tile + S accumulation
  auto writeP = [&](f32x4 e0, f32x4 e1, char* Pw) {
    const float p0 = fexp2(e0[0]), p1 = fexp2(e0[1]);
    const float p2 = fexp2(e0[2]), p3 = fexp2(e0[3]);
    Sacc += (p0 + p1) + (p2 + p3);
    *(uint2*)(Pw + ((qrow * 128 + kh * 64 + quad * 8) ^ swz)) =
        make_uint2(cvtpk(p0, p1), cvtpk(p2, p3));
    const float s0 = fexp2(e1[0]), s1 = fexp2(e1[1]);
    const float s2 = fexp2(e1[2]), s3 = fexp2(e1[3]);
    Sacc += (s0 + s1) + (s2 + s3);
    *(uint2*)(Pw + ((qrow * 128 + kh * 64 + 32 + quad * 8) ^ swz)) =
        make_uint2(cvtpk(s0, s1), cvtpk(s2, s3));
  };

  loadK(0);
  loadV(0);

  // ---- prologue: QK(0) -> P(0) ----
  {
    f32x4 e0 = MFMA(kf[0][0], aq0, CINIT);
    e0 = MFMA(kf[0][1], aq1, e0);
    f32x4 e1 = MFMA(kf[1][0], aq0, CINIT);
    e1 = MFMA(kf[1][1], aq1, e1);
    writeP(e0, e1, (char*)Ps[0]);
  }
  loadK(1);
  asm volatile("s_waitcnt lgkmcnt(0)" ::: "memory");
  __builtin_amdgcn_s_barrier();
  asm volatile("" ::: "memory");

  for (int it = 0; it < 64; ++it) {
    char* Prd = (char*)Ps[it & 1];
    char* Pwr = (char*)Ps[(it + 1) & 1];
    // P(t) frags for PV kc=0 — independent of the QK(t+1) chain below
    bf16x8 bp0[4];
#pragma unroll
    for (int nt = 0; nt < 4; ++nt)
      bp0[nt] = *(const bf16x8*)(Prd + ((((nt * 16 + ln) * 128 + quad * 16)) ^ swz));
    if (it < 63) {
      // QK(t+1) on prefetched kf
      __builtin_amdgcn_s_setprio(1);
      f32x4 e0 = MFMA(kf[0][0], aq0, CINIT);
      e0 = MFMA(kf[0][1], aq1, e0);
      f32x4 e1 = MFMA(kf[1][0], aq0, CINIT);
      e1 = MFMA(kf[1][1], aq1, e1);
      __builtin_amdgcn_s_setprio(0);
      if (it < 62) loadK(it + 2);
      writeP(e0, e1, Pwr);
    }
    // PV(t) kc=0
    __builtin_amdgcn_s_setprio(1);
#pragma unroll
    for (int mt = 0; mt < 2; ++mt)
#pragma unroll
      for (int nt = 0; nt < 4; ++nt)
        acc[mt][nt] = MFMA(vf[mt][0], bp0[nt], acc[mt][nt]);
    __builtin_amdgcn_s_setprio(0);
    // PV(t) kc=1
    bf16x8 bp1[4];
#pragma unroll
    for (int nt = 0; nt < 4; ++nt)
      bp1[nt] = *(const bf16x8*)(Prd + ((((nt * 16 + ln) * 128 + 64 + quad * 16)) ^ swz));
    __builtin_amdgcn_s_setprio(1);
#pragma unroll
    for (int mt = 0; mt < 2; ++mt)
#pragma unroll
      for (int nt = 0; nt < 4; ++nt)
        acc[mt][nt] = MFMA(vf[mt][1], bp1[nt], acc[mt][nt]);
    __builtin_amdgcn_s_setprio(0);
    if (it < 63) {
      loadV(it + 1);                      // vf dead after PV(t)
      asm volatile("s_waitcnt lgkmcnt(0)" ::: "memory");
      __builtin_amdgcn_s_barrier();
      asm volatile("" ::: "memory");
    }
  }

  // ---- S reduce (sum over quads = this wave's k range) + epilogue ----
  {
    float s = Sacc;
    s += __shfl_xor(s, 16);
    s += __shfl_xor(s, 32);
    if (quad == 0) Red[kh][qrow] = s;
  }
  __syncthreads();
  float rsv[4];
#pragma unroll
  for (int nt = 0; nt < 4; ++nt)
    rsv[nt] = 1.0f / (Red[0][nt * 16 + ln] + Red[1][nt * 16 + ln]);

  const float g = gamma[0];
#pragma unroll
  for (int mt = 0; mt < 2; ++mt) {
#pragma unroll
    for (int r = 0; r < 4; ++r) {
      const int ch = ch0 + w * 32 + mt * 16 + quad * 4 + r;
      const size_t base = ((size_t)b * C_ + ch) * HW_ + q0;
#pragma unroll
      for (int nt = 0; nt < 4; ++nt) {
        const size_t idx = base + nt * 16 + ln;
        out[idx] = g * (acc[mt][nt][r] * rsv[nt]) + fe[idx];
      }
    }
  }
}

// ---------------------------------------------------------------------------
extern "C" void kernel_launch(void* const* d_in, const int* in_sizes, int n_in,
                              void* d_out, int out_size, void* d_ws, size_t ws_size,
                              hipStream_t stream) {
  const float* fe    = (const float*)d_in[0];
  const float* total = (const float*)d_in[1];
  const float* Wq    = (const float*)d_in[2];
  const float* bq    = (const float*)d_in[3];
  const float* Wk    = (const float*)d_in[4];
  const float* bk    = (const float*)d_in[5];
  const float* Wv    = (const float*)d_in[6];
  const float* bv    = (const float*)d_in[7];
  const float* ht    = (const float*)d_in[8];
  const float* wt    = (const float*)d_in[9];
  const float* gamma = (const float*)d_in[10];
  float* out = (float*)d_out;

  // ws: Qhat 2MB | Khat 2MB | Vhat 16MB (fragment-major)
  unsigned short* Qh = (unsigned short*)d_ws;
  unsigned short* Kh = Qh + (size_t)B_ * HW_ * C8_;
  unsigned short* Vn = Kh + (size_t)B_ * HW_ * C8_;

  proj_kernel<<<dim3(64, 6, B_), 256, 0, stream>>>(total, fe, Wq, bq, Wk, bk,
                                                   Wv, bv, ht, wt, Qh, Kh, Vn);
  flash_kernel<<<dim3(512), 512, 0, stream>>>(Qh, Kh, Vn, fe, gamma, out);
}